// Round 7
// baseline (551.270 us; speedup 1.0000x reference)
//
#include <hip/hip_runtime.h>
#include <stdint.h>

#define S_LEN 2048
#define HD    128
#define NKV   8
#define NQM   4
#define WIN   1024
#define QB    32
#define KTILE 32
#define KVROW (NKV * HD)        /* 1024 elements per K/V token row */
#define QROW  (NQM * NKV * HD)  /* 4096 elements per Q/out token row */

typedef __attribute__((ext_vector_type(8))) short bf16x8;
typedef __attribute__((ext_vector_type(4))) float f32x4;
typedef __attribute__((ext_vector_type(4))) int   i32x4;

// pack two f32 -> one dword of 2 bf16 (lo, hi), single HW op
__device__ __forceinline__ uint32_t cvtpk(float lo, float hi) {
  uint32_t r;
  asm("v_cvt_pk_bf16_f32 %0, %1, %2" : "=v"(r) : "v"(lo), "v"(hi));
  return r;
}
// byte-permute: D bytes from {S0=a, S1=b}; sel values 0-3 = b bytes, 4-7 = a bytes
__device__ __forceinline__ uint32_t perm2(uint32_t a, uint32_t b, uint32_t sel) {
  uint32_t r;
  asm("v_perm_b32 %0, %1, %2, %3" : "=v"(r) : "v"(a), "v"(b), "s"(sel));
  return r;
}

// load 8 consecutive "bf16-worth" elements starting at p (packed 2/dword)
__device__ __forceinline__ void load8bf(const uint16_t* p, uint32_t o[4]) {
  i32x4 v = *reinterpret_cast<const i32x4*>(p);
  o[0] = (uint32_t)v[0]; o[1] = (uint32_t)v[1]; o[2] = (uint32_t)v[2]; o[3] = (uint32_t)v[3];
}
__device__ __forceinline__ void load8bf(const float* p, uint32_t o[4]) {
  float4 a = *reinterpret_cast<const float4*>(p);
  float4 b = *reinterpret_cast<const float4*>(p + 4);
  o[0] = cvtpk(a.x, a.y);
  o[1] = cvtpk(a.z, a.w);
  o[2] = cvtpk(b.x, b.y);
  o[3] = cvtpk(b.z, b.w);
}

// fused K+V fp32 -> bf16 conversion (one launch)
__global__ void cvt2_kernel(const float* __restrict__ inK, const float* __restrict__ inV,
                            uint16_t* __restrict__ outK, uint16_t* __restrict__ outV, int n4) {
  int i = blockIdx.x * blockDim.x + threadIdx.x;
  int stride = gridDim.x * blockDim.x;
  for (int j = i; j < 2 * n4; j += stride) {
    const float* in = (j < n4) ? inK : inV;
    uint16_t* out   = (j < n4) ? outK : outV;
    int jj = (j < n4) ? j : j - n4;
    float4 v = reinterpret_cast<const float4*>(in)[jj];
    uint2 o;
    o.x = cvtpk(v.x, v.y);
    o.y = cvtpk(v.z, v.w);
    reinterpret_cast<uint2*>(out)[jj] = o;
  }
}

// V^T LDS column swizzle: conflict-light for both the transpose-scatter
// writes (spread by d>>3) and the PV b-frag reads (spread by d&7)
#define VSWZ(d) (((((uint32_t)(d) >> 3) ^ (uint32_t)(d)) & 7u) << 3)

// K row permutation: physical LDS row a holds key KPERM(a). This makes the
// QK^T output fragment (keys g*8+kt_*4+r in lane g) coincide EXACTLY with the
// PV A-fragment layout (lane g needs keys g*8..g*8+7) -> P never touches LDS.
#define KPERM(a)  ((((a) >> 2) & 3) * 8 + ((a) >> 4) * 4 + ((a) & 3))
#define KPERMI(k) ((((k) >> 2) & 1) * 16 + ((k) >> 3) * 4 + ((k) & 3))

template <typename KVT>
__launch_bounds__(256, 4)
__global__ void attn_kernel(const float* __restrict__ Q,
                            const KVT* __restrict__ Ksrc,
                            const KVT* __restrict__ Vsrc,
                            const float* __restrict__ sinks,
                            float* __restrict__ out) {
  // LDS: K tiles  2 x (32 x 256B, 16B-swizzled, KPERM'd rows) : 16 KB @ 0
  //      V^T tiles 2 x (128 x 64B, 8B-swizzled)               : 16 KB @ 16384
  __shared__ __align__(16) uint8_t smem[32768];

  const int tid  = threadIdx.x;
  const int lane = tid & 63;
  const int wv   = tid >> 6;
  const int c    = lane & 15;   // "16-dim" lane coordinate
  const int g    = lane >> 4;   // lane group 0..3

  // ---- block decode: kv = bid&7 keeps each kv's K/V on one XCD's L2 ----
  const int bid = blockIdx.x;
  const int kv  = bid & 7;
  const int i2  = bid >> 3;          // 0 .. 48*B-1
  const int b   = i2 / 48;
  const int pairIdx = i2 % 48;
  const int head = kv * NQM + wv;
  const float sink_l2 = sinks[head] * 1.4426950408889634f;

  // tile pairing: work(qt) = qt+1 tiles for qt<32, 33 for qt>=32.
  // pair (31-p, p) -> 33; singles 32..63 -> 33. Every block = 33 k-iters.
  int qtA, qtB, nrep;
  if (pairIdx < 16) { qtA = 31 - pairIdx; qtB = pairIdx; nrep = 2; }
  else              { qtA = pairIdx + 16; qtB = 0;       nrep = 1; }

  // ---------------- staging coordinates ----------------
  const size_t kbase = (size_t)(b * S_LEN) * KVROW + kv * HD;   // elems
  // bf16 path: per-lane invariant global byte offsets (row -> KPERM'd key)
  uint32_t kgo[2];
  #pragma unroll
  for (int ch = 0; ch < 2; ++ch) {
    const int o    = wv * 2048 + ch * 1024 + lane * 16;
    const int row  = o >> 8;
    const int key  = KPERM(row);
    const int scol = (o & 255) ^ ((row & 7) << 4);
    kgo[ch] = (uint32_t)(key * (KVROW * 2) + scol);
  }
  // fp32 path: thread covers key row kr, writes at physical row KPERMI(kr)
  const int kr  = tid >> 3;
  const int kcB = (tid & 7) * 32;
  const int kpr = KPERMI(kr);
  const uint32_t kw0 = (uint32_t)(kpr * 256 + ((kcB)      ^ ((kpr & 7) << 4)));
  const uint32_t kw1 = (uint32_t)(kpr * 256 + ((kcB + 16) ^ ((kpr & 7) << 4)));
  const KVT* kg = Ksrc + kbase + (tid & 7) * 16;
  const int va = tid >> 4;             // V key-pair 0..15
  const int vd = tid & 15;             // V d-chunk
  const KVT* vg = Vsrc + kbase + vd * 8;

  uint32_t vr0[4], vr1[4];

  // async K stage: linear LDS dest (wave-uniform base + lane*16), KPERM+swizzle
  // applied on the per-lane GLOBAL source address (m173 pattern)
  auto stageK = [&](uint8_t* kbuf, int kt) {
    if constexpr (sizeof(KVT) == 2) {
      const uint8_t* kb = (const uint8_t*)(Ksrc + kbase) + (size_t)kt * (KVROW * 2);
      #pragma unroll
      for (int ch = 0; ch < 2; ++ch) {
        __builtin_amdgcn_global_load_lds(
            (const __attribute__((address_space(1))) void*)(kb + kgo[ch]),
            (__attribute__((address_space(3))) void*)(kbuf + wv * 2048 + ch * 1024),
            16, 0, 0);
      }
    } else {
      const KVT* src = kg + (size_t)(kt + kr) * KVROW;
      uint32_t t0[4], t1[4];
      load8bf(src, t0); load8bf(src + 8, t1);
      i32x4 w0, w1;
      w0[0]=(int)t0[0]; w0[1]=(int)t0[1]; w0[2]=(int)t0[2]; w0[3]=(int)t0[3];
      w1[0]=(int)t1[0]; w1[1]=(int)t1[1]; w1[2]=(int)t1[2]; w1[3]=(int)t1[3];
      *reinterpret_cast<i32x4*>(kbuf + kw0) = w0;
      *reinterpret_cast<i32x4*>(kbuf + kw1) = w1;
    }
  };
  auto loadV = [&](int kt) {
    const KVT* vs = vg + (size_t)(kt + 2 * va) * KVROW;
    load8bf(vs, vr0); load8bf(vs + KVROW, vr1);
  };
  // transpose-repack via v_perm_b32: out dword d = {r1.half, r0.half}
  auto writeV = [&](uint8_t* vbuf) {
    #pragma unroll
    for (int ii = 0; ii < 8; ++ii) {
      int d = vd * 8 + ii;
      uint32_t w = (ii & 1) ? perm2(vr1[ii >> 1], vr0[ii >> 1], 0x07060302u)
                            : perm2(vr1[ii >> 1], vr0[ii >> 1], 0x05040100u);
      uint32_t byte = (uint32_t)(d * 64) + (((uint32_t)(va * 4)) ^ VSWZ(d));
      *reinterpret_cast<uint32_t*>(vbuf + byte) = w;
    }
  };

  const float SCALE2 = 0.08838834764831845f * 1.4426950408889634f;  // 1/sqrt(128)*log2e

  for (int rep = 0; rep < nrep; ++rep) {
    const int q0 = (rep ? qtB : qtA) * QB;

    // -------- Q fragments (bf16, SM_SCALE*log2e folded in) --------
    bf16x8 qf[2][4];
    #pragma unroll
    for (int tq = 0; tq < 2; ++tq) {
      const float* qp = Q + (size_t)(b * S_LEN + q0 + tq * 16 + c) * QROW + head * HD;
      #pragma unroll
      for (int f = 0; f < 4; ++f) {
        int d0 = f * 32 + g * 8;
        float4 a = *reinterpret_cast<const float4*>(qp + d0);
        float4 bb = *reinterpret_cast<const float4*>(qp + d0 + 4);
        i32x4 t;
        t[0] = (int)cvtpk(a.x * SCALE2, a.y * SCALE2);
        t[1] = (int)cvtpk(a.z * SCALE2, a.w * SCALE2);
        t[2] = (int)cvtpk(bb.x * SCALE2, bb.y * SCALE2);
        t[3] = (int)cvtpk(bb.z * SCALE2, bb.w * SCALE2);
        qf[tq][f] = __builtin_bit_cast(bf16x8, t);
      }
    }

    // online-softmax state (log2 domain); sink = initial column with weight 1,
    // split 0.25 per g-lane (lp is a per-lane partial of l, reduced at epilogue)
    float m_[2] = {sink_l2, sink_l2};
    float lp_[2] = {0.25f, 0.25f};
    f32x4 acc[2][8];
    #pragma unroll
    for (int tq = 0; tq < 2; ++tq)
      #pragma unroll
      for (int dt = 0; dt < 8; ++dt) acc[tq][dt] = (f32x4)0.0f;

    int kstart = q0 - (WIN - 1);
    if (kstart < 0) kstart = 0;
    kstart &= ~(KTILE - 1);

    uint8_t* kcur = smem;         uint8_t* kalt = smem + 8192;
    uint8_t* vcur = smem + 16384; uint8_t* valt = smem + 24576;

    // prologue: stage first tile
    loadV(kstart);
    stageK(kcur, kstart);
    writeV(vcur);
    __syncthreads();

    for (int kt = kstart; kt <= q0; kt += KTILE) {
      // unconditional clamped prefetch (last iter re-loads current tile; harmless)
      const int ktn = (kt + KTILE <= q0) ? (kt + KTILE) : kt;
      stageK(kalt, ktn);
      loadV(ktn);

      // ---- QK^T (swapped: St[key-slot][q]) ----
      f32x4 st[2][2];
      #pragma unroll
      for (int a_ = 0; a_ < 2; ++a_)
        #pragma unroll
        for (int b_ = 0; b_ < 2; ++b_) st[a_][b_] = (f32x4)0.0f;

      __builtin_amdgcn_s_setprio(1);
      #pragma unroll
      for (int kt_ = 0; kt_ < 2; ++kt_) {
        bf16x8 kf[4];
        #pragma unroll
        for (int f = 0; f < 4; ++f) {
          int row = kt_ * 16 + c;
          uint32_t byte = (uint32_t)(row * 256 + ((f * 64 + g * 16) ^ ((row & 7) << 4)));
          kf[f] = *reinterpret_cast<const bf16x8*>(kcur + byte);
        }
        #pragma unroll
        for (int tq = 0; tq < 2; ++tq)
          #pragma unroll
          for (int f = 0; f < 4; ++f)
            st[kt_][tq] = __builtin_amdgcn_mfma_f32_16x16x32_bf16(kf[f], qf[tq][f], st[kt_][tq], 0, 0, 0);
      }
      __builtin_amdgcn_s_setprio(0);

      // ---- mask (edge tiles only; wave-uniform branch) ----
      // with KPERM, output element (kt_, r) of lane g is key g*8 + kt_*4 + r
      const bool need_mask = (kt + KTILE - 1 > q0) || (kt < q0 + QB - WIN);
      if (need_mask) {
        #pragma unroll
        for (int kt_ = 0; kt_ < 2; ++kt_)
          #pragma unroll
          for (int tq = 0; tq < 2; ++tq)
            #pragma unroll
            for (int r = 0; r < 4; ++r) {
              int k_ = kt + g * 8 + kt_ * 4 + r;
              int q_ = q0 + tq * 16 + c;
              bool ok = (k_ <= q_) && (k_ > q_ - WIN);
              if (!ok) st[kt_][tq][r] = -1e38f;
            }
      }

      // ---- online softmax (log2 domain, defer-rescale, lazy cross-lane),
      //      P assembled DIRECTLY into the PV A-fragment (no LDS round-trip) ----
      bf16x8 pa[2];
      #pragma unroll
      for (int tq = 0; tq < 2; ++tq) {
        float ownmax = fmaxf(fmaxf(fmaxf(st[0][tq][0], st[0][tq][1]), fmaxf(st[0][tq][2], st[0][tq][3])),
                             fmaxf(fmaxf(st[1][tq][0], st[1][tq][1]), fmaxf(st[1][tq][2], st[1][tq][3])));
        const float mold = m_[tq];
        // wave-wide check needs no row reduction: all-lanes-below == all-rows-below
        if (!__all(ownmax <= mold + 11.54f)) {   // T13: P bounded by 2^11.54 = e^8
          float vmax = fmaxf(ownmax, __shfl_xor(ownmax, 16));
          vmax = fmaxf(vmax, __shfl_xor(vmax, 32));
          float mnew = fmaxf(mold, vmax);
          float scl  = exp2f(mold - mnew);
          m_[tq] = mnew;
          lp_[tq] *= scl;
          float sc[4];
          #pragma unroll
          for (int r = 0; r < 4; ++r) sc[r] = __shfl(scl, (lane & 48) | (g * 4 + r));
          #pragma unroll
          for (int dt = 0; dt < 8; ++dt)
            #pragma unroll
            for (int r = 0; r < 4; ++r) acc[tq][dt][r] *= sc[r];
        }
        const float mrun = m_[tq];
        float p[2][4];
        float s = 0.0f;
        #pragma unroll
        for (int kt_ = 0; kt_ < 2; ++kt_)
          #pragma unroll
          for (int r = 0; r < 4; ++r) {
            float e = exp2f(st[kt_][tq][r] - mrun);
            p[kt_][r] = e;
            s += e;
          }
        lp_[tq] += s;                       // per-lane partial; reduced at epilogue
        i32x4 pv;
        pv[0] = (int)cvtpk(p[0][0], p[0][1]);   // keys g*8+0, g*8+1
        pv[1] = (int)cvtpk(p[0][2], p[0][3]);   // keys g*8+2, g*8+3
        pv[2] = (int)cvtpk(p[1][0], p[1][1]);   // keys g*8+4, g*8+5
        pv[3] = (int)cvtpk(p[1][2], p[1][3]);   // keys g*8+6, g*8+7
        pa[tq] = __builtin_bit_cast(bf16x8, pv);
      }

      // ---- PV ----
      __builtin_amdgcn_s_setprio(1);
      #pragma unroll
      for (int dt = 0; dt < 8; ++dt) {
        int d = dt * 16 + c;
        uint32_t rowb = (uint32_t)(d * 64);
        uint32_t swz  = VSWZ(d);
        uint2 lo = *reinterpret_cast<const uint2*>(vcur + rowb + (((uint32_t)(g * 16))     ^ swz));
        uint2 hi = *reinterpret_cast<const uint2*>(vcur + rowb + (((uint32_t)(g * 16 + 8)) ^ swz));
        i32x4 vv; vv[0] = (int)lo.x; vv[1] = (int)lo.y; vv[2] = (int)hi.x; vv[3] = (int)hi.y;
        bf16x8 vf = __builtin_bit_cast(bf16x8, vv);
        #pragma unroll
        for (int tq = 0; tq < 2; ++tq)
          acc[tq][dt] = __builtin_amdgcn_mfma_f32_16x16x32_bf16(pa[tq], vf, acc[tq][dt], 0, 0, 0);
      }
      __builtin_amdgcn_s_setprio(0);

      // ---- write next V tile into alternate buffer (T14 write-late) ----
      writeV(valt);
      __syncthreads();
      uint8_t* t0 = kcur; kcur = kalt; kalt = t0;
      uint8_t* t1 = vcur; vcur = valt; valt = t1;
    }

    // -------- epilogue: reduce l across g-lanes, O /= l, store --------
    #pragma unroll
    for (int tq = 0; tq < 2; ++tq) {
      float lt = lp_[tq];
      lt += __shfl_xor(lt, 16);
      lt += __shfl_xor(lt, 32);
      float linv = 1.0f / lt;
      float li[4];
      #pragma unroll
      for (int r = 0; r < 4; ++r) li[r] = __shfl(linv, (lane & 48) | (g * 4 + r));
      #pragma unroll
      for (int dt = 0; dt < 8; ++dt)
        #pragma unroll
        for (int r = 0; r < 4; ++r) {
          size_t o = (size_t)(b * S_LEN + q0 + tq * 16 + g * 4 + r) * QROW + head * HD + dt * 16 + c;
          out[o] = acc[tq][dt][r] * li[r];
        }
    }
  }
}

extern "C" void kernel_launch(void* const* d_in, const int* in_sizes, int n_in,
                              void* d_out, int out_size, void* d_ws, size_t ws_size,
                              hipStream_t stream) {
  const float* Q     = (const float*)d_in[0];
  const float* K     = (const float*)d_in[1];
  const float* V     = (const float*)d_in[2];
  const float* sinks = (const float*)d_in[3];
  float* out = (float*)d_out;

  const int nK = in_sizes[1];                       // B*S*NKV*HD
  const int B  = in_sizes[0] / (S_LEN * QROW);
  dim3 grid(384 * B);                               // 48 uniform blocks per (kv,b)

  const size_t need = (size_t)nK * 2u * 2u;         // Kbf + Vbf in bf16
  if (ws_size >= need) {
    uint16_t* Kb = (uint16_t*)d_ws;
    uint16_t* Vb = Kb + nK;
    cvt2_kernel<<<1024, 256, 0, stream>>>(K, V, Kb, Vb, nK / 4);
    attn_kernel<uint16_t><<<grid, 256, 0, stream>>>(Q, Kb, Vb, sinks, out);
  } else {
    attn_kernel<float><<<grid, 256, 0, stream>>>(Q, K, V, sinks, out);
  }
}

// Round 8
// 219.084 us; speedup vs baseline: 2.5163x; 2.5163x over previous
//
#include <hip/hip_runtime.h>
#include <stdint.h>

#define S_LEN 2048
#define HD    128
#define NKV   8
#define NQM   4
#define WIN   1024
#define QB    32
#define KTILE 32
#define KVROW (NKV * HD)        /* 1024 elements per K/V token row */
#define QROW  (NQM * NKV * HD)  /* 4096 elements per Q/out token row */

typedef __attribute__((ext_vector_type(8))) short bf16x8;
typedef __attribute__((ext_vector_type(4))) float f32x4;
typedef __attribute__((ext_vector_type(4))) int   i32x4;

// pack two f32 -> one dword of 2 bf16 (lo, hi), single HW op
__device__ __forceinline__ uint32_t cvtpk(float lo, float hi) {
  uint32_t r;
  asm("v_cvt_pk_bf16_f32 %0, %1, %2" : "=v"(r) : "v"(lo), "v"(hi));
  return r;
}
// byte-permute: D bytes from {S0=a, S1=b}; sel values 0-3 = b bytes, 4-7 = a bytes
__device__ __forceinline__ uint32_t perm2(uint32_t a, uint32_t b, uint32_t sel) {
  uint32_t r;
  asm("v_perm_b32 %0, %1, %2, %3" : "=v"(r) : "v"(a), "v"(b), "s"(sel));
  return r;
}

// load 8 consecutive "bf16-worth" elements starting at p (packed 2/dword)
__device__ __forceinline__ void load8bf(const uint16_t* p, uint32_t o[4]) {
  i32x4 v = *reinterpret_cast<const i32x4*>(p);
  o[0] = (uint32_t)v[0]; o[1] = (uint32_t)v[1]; o[2] = (uint32_t)v[2]; o[3] = (uint32_t)v[3];
}
__device__ __forceinline__ void load8bf(const float* p, uint32_t o[4]) {
  float4 a = *reinterpret_cast<const float4*>(p);
  float4 b = *reinterpret_cast<const float4*>(p + 4);
  o[0] = cvtpk(a.x, a.y);
  o[1] = cvtpk(a.z, a.w);
  o[2] = cvtpk(b.x, b.y);
  o[3] = cvtpk(b.z, b.w);
}

// fused K+V fp32 -> bf16 conversion (one launch)
__global__ void cvt2_kernel(const float* __restrict__ inK, const float* __restrict__ inV,
                            uint16_t* __restrict__ outK, uint16_t* __restrict__ outV, int n4) {
  int i = blockIdx.x * blockDim.x + threadIdx.x;
  int stride = gridDim.x * blockDim.x;
  for (int j = i; j < 2 * n4; j += stride) {
    const float* in = (j < n4) ? inK : inV;
    uint16_t* out   = (j < n4) ? outK : outV;
    int jj = (j < n4) ? j : j - n4;
    float4 v = reinterpret_cast<const float4*>(in)[jj];
    uint2 o;
    o.x = cvtpk(v.x, v.y);
    o.y = cvtpk(v.z, v.w);
    reinterpret_cast<uint2*>(out)[jj] = o;
  }
}

// V^T LDS column swizzle: conflict-light for both the transpose-scatter
// writes (spread by d>>3) and the PV b-frag reads (spread by d&7)
#define VSWZ(d) (((((uint32_t)(d) >> 3) ^ (uint32_t)(d)) & 7u) << 3)

// K row permutation: physical LDS row a holds key KPERM(a). This makes the
// QK^T output fragment (keys g*8+kt_*4+r in lane g) coincide EXACTLY with the
// PV A-fragment layout (lane g needs keys g*8..g*8+7) -> P never touches LDS.
#define KPERM(a)  ((((a) >> 2) & 3) * 8 + ((a) >> 4) * 4 + ((a) & 3))
#define KPERMI(k) ((((k) >> 2) & 1) * 16 + ((k) >> 3) * 4 + ((k) & 3))

// NOTE: do NOT tighten launch bounds. This kernel's live state is ~110 VGPRs;
// (256,4) forced a 64-VGPR allocation in r7 -> acc[] spilled to scratch ->
// FETCH 43MB->1.18GB, dur 122->447us. Occupancy must come from LDS/grid only.
template <typename KVT>
__launch_bounds__(256, 2)
__global__ void attn_kernel(const float* __restrict__ Q,
                            const KVT* __restrict__ Ksrc,
                            const KVT* __restrict__ Vsrc,
                            const float* __restrict__ sinks,
                            float* __restrict__ out) {
  // LDS: K tiles  2 x (32 x 256B, 16B-swizzled, KPERM'd rows) : 16 KB @ 0
  //      V^T tiles 2 x (128 x 64B, 8B-swizzled)               : 16 KB @ 16384
  __shared__ __align__(16) uint8_t smem[32768];

  const int tid  = threadIdx.x;
  const int lane = tid & 63;
  const int wv   = tid >> 6;
  const int c    = lane & 15;   // "16-dim" lane coordinate
  const int g    = lane >> 4;   // lane group 0..3

  // ---- block decode: kv = bid&7 keeps each kv's K/V on one XCD's L2 ----
  const int bid = blockIdx.x;
  const int kv  = bid & 7;
  const int i2  = bid >> 3;          // 0 .. 48*B-1
  const int b   = i2 / 48;
  const int pairIdx = i2 % 48;
  const int head = kv * NQM + wv;
  const float sink_l2 = sinks[head] * 1.4426950408889634f;

  // tile pairing: work(qt) = qt+1 tiles for qt<32, 33 for qt>=32.
  // pair (31-p, p) -> 33; singles 32..63 -> 33. Every block = 33 k-iters.
  int qtA, qtB, nrep;
  if (pairIdx < 16) { qtA = 31 - pairIdx; qtB = pairIdx; nrep = 2; }
  else              { qtA = pairIdx + 16; qtB = 0;       nrep = 1; }

  // ---------------- staging coordinates ----------------
  const size_t kbase = (size_t)(b * S_LEN) * KVROW + kv * HD;   // elems
  // bf16 path: per-lane invariant global byte offsets (row -> KPERM'd key)
  uint32_t kgo[2];
  #pragma unroll
  for (int ch = 0; ch < 2; ++ch) {
    const int o    = wv * 2048 + ch * 1024 + lane * 16;
    const int row  = o >> 8;
    const int key  = KPERM(row);
    const int scol = (o & 255) ^ ((row & 7) << 4);
    kgo[ch] = (uint32_t)(key * (KVROW * 2) + scol);
  }
  // fp32 path: thread covers key row kr, writes at physical row KPERMI(kr)
  const int kr  = tid >> 3;
  const int kcB = (tid & 7) * 32;
  const int kpr = KPERMI(kr);
  const uint32_t kw0 = (uint32_t)(kpr * 256 + ((kcB)      ^ ((kpr & 7) << 4)));
  const uint32_t kw1 = (uint32_t)(kpr * 256 + ((kcB + 16) ^ ((kpr & 7) << 4)));
  const KVT* kg = Ksrc + kbase + (tid & 7) * 16;
  const int va = tid >> 4;             // V key-pair 0..15
  const int vd = tid & 15;             // V d-chunk
  const KVT* vg = Vsrc + kbase + vd * 8;

  uint32_t vr0[4], vr1[4];

  // async K stage: linear LDS dest (wave-uniform base + lane*16), KPERM+swizzle
  // applied on the per-lane GLOBAL source address (m173 pattern)
  auto stageK = [&](uint8_t* kbuf, int kt) {
    if constexpr (sizeof(KVT) == 2) {
      const uint8_t* kb = (const uint8_t*)(Ksrc + kbase) + (size_t)kt * (KVROW * 2);
      #pragma unroll
      for (int ch = 0; ch < 2; ++ch) {
        __builtin_amdgcn_global_load_lds(
            (const __attribute__((address_space(1))) void*)(kb + kgo[ch]),
            (__attribute__((address_space(3))) void*)(kbuf + wv * 2048 + ch * 1024),
            16, 0, 0);
      }
    } else {
      const KVT* src = kg + (size_t)(kt + kr) * KVROW;
      uint32_t t0[4], t1[4];
      load8bf(src, t0); load8bf(src + 8, t1);
      i32x4 w0, w1;
      w0[0]=(int)t0[0]; w0[1]=(int)t0[1]; w0[2]=(int)t0[2]; w0[3]=(int)t0[3];
      w1[0]=(int)t1[0]; w1[1]=(int)t1[1]; w1[2]=(int)t1[2]; w1[3]=(int)t1[3];
      *reinterpret_cast<i32x4*>(kbuf + kw0) = w0;
      *reinterpret_cast<i32x4*>(kbuf + kw1) = w1;
    }
  };
  auto loadV = [&](int kt) {
    const KVT* vs = vg + (size_t)(kt + 2 * va) * KVROW;
    load8bf(vs, vr0); load8bf(vs + KVROW, vr1);
  };
  // transpose-repack via v_perm_b32: out dword d = {r1.half, r0.half}
  auto writeV = [&](uint8_t* vbuf) {
    #pragma unroll
    for (int ii = 0; ii < 8; ++ii) {
      int d = vd * 8 + ii;
      uint32_t w = (ii & 1) ? perm2(vr1[ii >> 1], vr0[ii >> 1], 0x07060302u)
                            : perm2(vr1[ii >> 1], vr0[ii >> 1], 0x05040100u);
      uint32_t byte = (uint32_t)(d * 64) + (((uint32_t)(va * 4)) ^ VSWZ(d));
      *reinterpret_cast<uint32_t*>(vbuf + byte) = w;
    }
  };

  const float SCALE2 = 0.08838834764831845f * 1.4426950408889634f;  // 1/sqrt(128)*log2e

  for (int rep = 0; rep < nrep; ++rep) {
    const int q0 = (rep ? qtB : qtA) * QB;

    // -------- Q fragments (bf16, SM_SCALE*log2e folded in) --------
    bf16x8 qf[2][4];
    #pragma unroll
    for (int tq = 0; tq < 2; ++tq) {
      const float* qp = Q + (size_t)(b * S_LEN + q0 + tq * 16 + c) * QROW + head * HD;
      #pragma unroll
      for (int f = 0; f < 4; ++f) {
        int d0 = f * 32 + g * 8;
        float4 a = *reinterpret_cast<const float4*>(qp + d0);
        float4 bb = *reinterpret_cast<const float4*>(qp + d0 + 4);
        i32x4 t;
        t[0] = (int)cvtpk(a.x * SCALE2, a.y * SCALE2);
        t[1] = (int)cvtpk(a.z * SCALE2, a.w * SCALE2);
        t[2] = (int)cvtpk(bb.x * SCALE2, bb.y * SCALE2);
        t[3] = (int)cvtpk(bb.z * SCALE2, bb.w * SCALE2);
        qf[tq][f] = __builtin_bit_cast(bf16x8, t);
      }
    }

    // online-softmax state (log2 domain); sink = initial column with weight 1,
    // split 0.25 per g-lane (lp is a per-lane partial of l, reduced at epilogue)
    float m_[2] = {sink_l2, sink_l2};
    float lp_[2] = {0.25f, 0.25f};
    f32x4 acc[2][8];
    #pragma unroll
    for (int tq = 0; tq < 2; ++tq)
      #pragma unroll
      for (int dt = 0; dt < 8; ++dt) acc[tq][dt] = (f32x4)0.0f;

    int kstart = q0 - (WIN - 1);
    if (kstart < 0) kstart = 0;
    kstart &= ~(KTILE - 1);

    uint8_t* kcur = smem;         uint8_t* kalt = smem + 8192;
    uint8_t* vcur = smem + 16384; uint8_t* valt = smem + 24576;

    // prologue: stage first tile
    loadV(kstart);
    stageK(kcur, kstart);
    writeV(vcur);
    __syncthreads();

    for (int kt = kstart; kt <= q0; kt += KTILE) {
      // unconditional clamped prefetch (last iter re-loads current tile; harmless)
      const int ktn = (kt + KTILE <= q0) ? (kt + KTILE) : kt;
      stageK(kalt, ktn);
      loadV(ktn);

      // ---- QK^T (swapped: St[key-slot][q]) ----
      f32x4 st[2][2];
      #pragma unroll
      for (int a_ = 0; a_ < 2; ++a_)
        #pragma unroll
        for (int b_ = 0; b_ < 2; ++b_) st[a_][b_] = (f32x4)0.0f;

      __builtin_amdgcn_s_setprio(1);
      #pragma unroll
      for (int kt_ = 0; kt_ < 2; ++kt_) {
        bf16x8 kf[4];
        #pragma unroll
        for (int f = 0; f < 4; ++f) {
          int row = kt_ * 16 + c;
          uint32_t byte = (uint32_t)(row * 256 + ((f * 64 + g * 16) ^ ((row & 7) << 4)));
          kf[f] = *reinterpret_cast<const bf16x8*>(kcur + byte);
        }
        #pragma unroll
        for (int tq = 0; tq < 2; ++tq)
          #pragma unroll
          for (int f = 0; f < 4; ++f)
            st[kt_][tq] = __builtin_amdgcn_mfma_f32_16x16x32_bf16(kf[f], qf[tq][f], st[kt_][tq], 0, 0, 0);
      }
      __builtin_amdgcn_s_setprio(0);

      // ---- mask (edge tiles only; wave-uniform branch) ----
      // with KPERM, output element (kt_, r) of lane g is key g*8 + kt_*4 + r
      const bool need_mask = (kt + KTILE - 1 > q0) || (kt < q0 + QB - WIN);
      if (need_mask) {
        #pragma unroll
        for (int kt_ = 0; kt_ < 2; ++kt_)
          #pragma unroll
          for (int tq = 0; tq < 2; ++tq)
            #pragma unroll
            for (int r = 0; r < 4; ++r) {
              int k_ = kt + g * 8 + kt_ * 4 + r;
              int q_ = q0 + tq * 16 + c;
              bool ok = (k_ <= q_) && (k_ > q_ - WIN);
              if (!ok) st[kt_][tq][r] = -1e38f;
            }
      }

      // ---- online softmax (log2 domain, defer-rescale, lazy cross-lane),
      //      P assembled DIRECTLY into the PV A-fragment (no LDS round-trip) ----
      bf16x8 pa[2];
      #pragma unroll
      for (int tq = 0; tq < 2; ++tq) {
        float ownmax = fmaxf(fmaxf(fmaxf(st[0][tq][0], st[0][tq][1]), fmaxf(st[0][tq][2], st[0][tq][3])),
                             fmaxf(fmaxf(st[1][tq][0], st[1][tq][1]), fmaxf(st[1][tq][2], st[1][tq][3])));
        const float mold = m_[tq];
        // wave-wide check needs no row reduction: all-lanes-below == all-rows-below
        if (!__all(ownmax <= mold + 11.54f)) {   // T13: P bounded by 2^11.54 = e^8
          float vmax = fmaxf(ownmax, __shfl_xor(ownmax, 16));
          vmax = fmaxf(vmax, __shfl_xor(vmax, 32));
          float mnew = fmaxf(mold, vmax);
          float scl  = exp2f(mold - mnew);
          m_[tq] = mnew;
          lp_[tq] *= scl;
          float sc[4];
          #pragma unroll
          for (int r = 0; r < 4; ++r) sc[r] = __shfl(scl, (lane & 48) | (g * 4 + r));
          #pragma unroll
          for (int dt = 0; dt < 8; ++dt)
            #pragma unroll
            for (int r = 0; r < 4; ++r) acc[tq][dt][r] *= sc[r];
        }
        const float mrun = m_[tq];
        float p[2][4];
        float s = 0.0f;
        #pragma unroll
        for (int kt_ = 0; kt_ < 2; ++kt_)
          #pragma unroll
          for (int r = 0; r < 4; ++r) {
            float e = exp2f(st[kt_][tq][r] - mrun);
            p[kt_][r] = e;
            s += e;
          }
        lp_[tq] += s;                       // per-lane partial; reduced at epilogue
        i32x4 pv;
        pv[0] = (int)cvtpk(p[0][0], p[0][1]);   // keys g*8+0, g*8+1
        pv[1] = (int)cvtpk(p[0][2], p[0][3]);   // keys g*8+2, g*8+3
        pv[2] = (int)cvtpk(p[1][0], p[1][1]);   // keys g*8+4, g*8+5
        pv[3] = (int)cvtpk(p[1][2], p[1][3]);   // keys g*8+6, g*8+7
        pa[tq] = __builtin_bit_cast(bf16x8, pv);
      }

      // ---- PV ----
      __builtin_amdgcn_s_setprio(1);
      #pragma unroll
      for (int dt = 0; dt < 8; ++dt) {
        int d = dt * 16 + c;
        uint32_t rowb = (uint32_t)(d * 64);
        uint32_t swz  = VSWZ(d);
        uint2 lo = *reinterpret_cast<const uint2*>(vcur + rowb + (((uint32_t)(g * 16))     ^ swz));
        uint2 hi = *reinterpret_cast<const uint2*>(vcur + rowb + (((uint32_t)(g * 16 + 8)) ^ swz));
        i32x4 vv; vv[0] = (int)lo.x; vv[1] = (int)lo.y; vv[2] = (int)hi.x; vv[3] = (int)hi.y;
        bf16x8 vf = __builtin_bit_cast(bf16x8, vv);
        #pragma unroll
        for (int tq = 0; tq < 2; ++tq)
          acc[tq][dt] = __builtin_amdgcn_mfma_f32_16x16x32_bf16(pa[tq], vf, acc[tq][dt], 0, 0, 0);
      }
      __builtin_amdgcn_s_setprio(0);

      // ---- write next V tile into alternate buffer (T14 write-late) ----
      writeV(valt);
      __syncthreads();
      uint8_t* t0 = kcur; kcur = kalt; kalt = t0;
      uint8_t* t1 = vcur; vcur = valt; valt = t1;
    }

    // -------- epilogue: reduce l across g-lanes, O /= l, store --------
    #pragma unroll
    for (int tq = 0; tq < 2; ++tq) {
      float lt = lp_[tq];
      lt += __shfl_xor(lt, 16);
      lt += __shfl_xor(lt, 32);
      float linv = 1.0f / lt;
      float li[4];
      #pragma unroll
      for (int r = 0; r < 4; ++r) li[r] = __shfl(linv, (lane & 48) | (g * 4 + r));
      #pragma unroll
      for (int dt = 0; dt < 8; ++dt)
        #pragma unroll
        for (int r = 0; r < 4; ++r) {
          size_t o = (size_t)(b * S_LEN + q0 + tq * 16 + g * 4 + r) * QROW + head * HD + dt * 16 + c;
          out[o] = acc[tq][dt][r] * li[r];
        }
    }
  }
}

extern "C" void kernel_launch(void* const* d_in, const int* in_sizes, int n_in,
                              void* d_out, int out_size, void* d_ws, size_t ws_size,
                              hipStream_t stream) {
  const float* Q     = (const float*)d_in[0];
  const float* K     = (const float*)d_in[1];
  const float* V     = (const float*)d_in[2];
  const float* sinks = (const float*)d_in[3];
  float* out = (float*)d_out;

  const int nK = in_sizes[1];                       // B*S*NKV*HD
  const int B  = in_sizes[0] / (S_LEN * QROW);
  dim3 grid(384 * B);                               // 48 uniform blocks per (kv,b)

  const size_t need = (size_t)nK * 2u * 2u;         // Kbf + Vbf in bf16
  if (ws_size >= need) {
    uint16_t* Kb = (uint16_t*)d_ws;
    uint16_t* Vb = Kb + nK;
    cvt2_kernel<<<1024, 256, 0, stream>>>(K, V, Kb, Vb, nK / 4);
    attn_kernel<uint16_t><<<grid, 256, 0, stream>>>(Q, Kb, Vb, sinks, out);
  } else {
    attn_kernel<float><<<grid, 256, 0, stream>>>(Q, K, V, sinks, out);
  }
}

// Round 9
// 200.070 us; speedup vs baseline: 2.7554x; 1.0950x over previous
//
#include <hip/hip_runtime.h>
#include <stdint.h>

#define S_LEN 2048
#define HD    128
#define NKV   8
#define NQM   4
#define WIN   1024
#define QB    32
#define KTILE 32
#define KVROW (NKV * HD)        /* 1024 elements per K/V token row */
#define QROW  (NQM * NKV * HD)  /* 4096 elements per Q/out token row */

typedef __attribute__((ext_vector_type(8))) short bf16x8;
typedef __attribute__((ext_vector_type(4))) float f32x4;
typedef __attribute__((ext_vector_type(4))) int   i32x4;
typedef __attribute__((ext_vector_type(2))) unsigned u32x2;

// pack two f32 -> one dword of 2 bf16 (lo, hi), single HW op
__device__ __forceinline__ uint32_t cvtpk(float lo, float hi) {
  uint32_t r;
  asm("v_cvt_pk_bf16_f32 %0, %1, %2" : "=v"(r) : "v"(lo), "v"(hi));
  return r;
}

// load 8 consecutive "bf16-worth" elements starting at p (packed 2/dword)
__device__ __forceinline__ void load8bf(const uint16_t* p, uint32_t o[4]) {
  i32x4 v = *reinterpret_cast<const i32x4*>(p);
  o[0] = (uint32_t)v[0]; o[1] = (uint32_t)v[1]; o[2] = (uint32_t)v[2]; o[3] = (uint32_t)v[3];
}
__device__ __forceinline__ void load8bf(const float* p, uint32_t o[4]) {
  float4 a = *reinterpret_cast<const float4*>(p);
  float4 b = *reinterpret_cast<const float4*>(p + 4);
  o[0] = cvtpk(a.x, a.y);
  o[1] = cvtpk(a.z, a.w);
  o[2] = cvtpk(b.x, b.y);
  o[3] = cvtpk(b.z, b.w);
}

// fused K+V fp32 -> bf16 conversion (one launch)
__global__ void cvt2_kernel(const float* __restrict__ inK, const float* __restrict__ inV,
                            uint16_t* __restrict__ outK, uint16_t* __restrict__ outV, int n4) {
  int i = blockIdx.x * blockDim.x + threadIdx.x;
  int stride = gridDim.x * blockDim.x;
  for (int j = i; j < 2 * n4; j += stride) {
    const float* in = (j < n4) ? inK : inV;
    uint16_t* out   = (j < n4) ? outK : outV;
    int jj = (j < n4) ? j : j - n4;
    float4 v = reinterpret_cast<const float4*>(in)[jj];
    uint2 o;
    o.x = cvtpk(v.x, v.y);
    o.y = cvtpk(v.z, v.w);
    reinterpret_cast<uint2*>(out)[jj] = o;
  }
}

// K row permutation: physical LDS row a holds key KPERM(a). This makes the
// QK^T output fragment (keys g*8+kt_*4+r in lane g) coincide EXACTLY with the
// PV A-fragment layout (lane g needs keys g*8..g*8+7) -> P never touches LDS.
#define KPERM(a)  ((((a) >> 2) & 3) * 8 + ((a) >> 4) * 4 + ((a) & 3))
#define KPERMI(k) ((((k) >> 2) & 1) * 16 + ((k) >> 3) * 4 + ((k) & 3))

// V subtiled layout for ds_read_b64_tr_b16 (m156/m162 layout):
//   elem(k, d) = D*512 + h*256 + g*64 + j*16 + c
//   with D=d>>4, c=d&15, g=k>>3, h=(k>>2)&1, j=k&3.
// A tr-read at per-lane addr = base + lane*8 (+ offset: D*1024 + h*512 bytes)
// delivers lane (c,g) elems j=0..3 of V[g*8+h*4+j][D*16+c] == the PV B-frag.

// NOTE: do NOT tighten launch bounds. Live state ~105 VGPRs; (256,4) forced a
// 64-VGPR allocation in r7 -> acc[] spilled -> FETCH 43MB->1.18GB, 122->447us.
template <typename KVT>
__launch_bounds__(256, 2)
__global__ void attn_kernel(const float* __restrict__ Q,
                            const KVT* __restrict__ Ksrc,
                            const KVT* __restrict__ Vsrc,
                            const float* __restrict__ sinks,
                            float* __restrict__ out) {
  // LDS: K tiles 2 x (32 x 256B, 16B-swizzled, KPERM'd rows) : 16 KB @ 0
  //      V tiles 2 x (8 KB, tr-subtiled)                     : 16 KB @ 16384
  __shared__ __align__(16) uint8_t smem[32768];

  const int tid  = threadIdx.x;
  const int lane = tid & 63;
  const int wv   = tid >> 6;
  const int c    = lane & 15;   // "16-dim" lane coordinate
  const int g    = lane >> 4;   // lane group 0..3

  // ---- block decode: kv = bid&7 keeps each kv's K/V on one XCD's L2 ----
  const int bid = blockIdx.x;
  const int kv  = bid & 7;
  const int i2  = bid >> 3;          // 0 .. 48*B-1
  const int b   = i2 / 48;
  const int pairIdx = i2 % 48;
  const int head = kv * NQM + wv;
  const float sink_l2 = sinks[head] * 1.4426950408889634f;

  // tile pairing: work(qt) = qt+1 tiles for qt<32, 33 for qt>=32.
  // pair (31-p, p) -> 33; singles 32..63 -> 33. Every block = 33 k-iters.
  int qtA, qtB, nrep;
  if (pairIdx < 16) { qtA = 31 - pairIdx; qtB = pairIdx; nrep = 2; }
  else              { qtA = pairIdx + 16; qtB = 0;       nrep = 1; }

  // ---------------- staging coordinates ----------------
  const size_t kbase = (size_t)(b * S_LEN) * KVROW + kv * HD;   // elems (K and V)
  // K (bf16): per-lane invariant global byte offsets (LDS row -> KPERM'd key)
  uint32_t kgo[2];
  #pragma unroll
  for (int ch = 0; ch < 2; ++ch) {
    const int o    = wv * 2048 + ch * 1024 + lane * 16;
    const int row  = o >> 8;
    const int key  = KPERM(row);
    const int scol = (o & 255) ^ ((row & 7) << 4);
    kgo[ch] = (uint32_t)(key * (KVROW * 2) + scol);
  }
  // V (bf16): per-lane invariant global byte offsets for the tr-subtiled layout
  uint32_t vgo[2];
  #pragma unroll
  for (int ch = 0; ch < 2; ++ch) {
    const int o16 = wv * 128 + ch * 64 + lane;   // 16B-chunk index 0..511
    const int c0  = (o16 & 1) * 8;
    const int j   = (o16 >> 1) & 3;
    const int g_  = (o16 >> 3) & 3;
    const int h   = (o16 >> 5) & 1;
    const int D   = o16 >> 6;
    const int k   = g_ * 8 + h * 4 + j;
    vgo[ch] = (uint32_t)((k * KVROW + D * 16 + c0) * 2);
  }
  // fp32 fallback coords
  const int kr  = tid >> 3;
  const int kcB = (tid & 7) * 32;
  const int kpr = KPERMI(kr);
  const uint32_t kw0 = (uint32_t)(kpr * 256 + ((kcB)      ^ ((kpr & 7) << 4)));
  const uint32_t kw1 = (uint32_t)(kpr * 256 + ((kcB + 16) ^ ((kpr & 7) << 4)));
  const KVT* kg = Ksrc + kbase + (tid & 7) * 16;
  const int va = tid >> 4;             // V key-pair 0..15
  const int vd = tid & 15;             // V d-chunk
  const KVT* vg = Vsrc + kbase + vd * 8;

  // LDS byte address (AS3 offset) of the V region, per-lane for tr reads
  const uint32_t vlane =
      (uint32_t)(uintptr_t)(__attribute__((address_space(3))) uint8_t*)(smem + 16384) + lane * 8;

  auto stageK = [&](uint8_t* kbuf, int kt) {
    if constexpr (sizeof(KVT) == 2) {
      const uint8_t* kb = (const uint8_t*)(Ksrc + kbase) + (size_t)kt * (KVROW * 2);
      #pragma unroll
      for (int ch = 0; ch < 2; ++ch) {
        __builtin_amdgcn_global_load_lds(
            (const __attribute__((address_space(1))) void*)(kb + kgo[ch]),
            (__attribute__((address_space(3))) void*)(kbuf + wv * 2048 + ch * 1024),
            16, 0, 0);
      }
    } else {
      const KVT* src = kg + (size_t)(kt + kr) * KVROW;
      uint32_t t0[4], t1[4];
      load8bf(src, t0); load8bf(src + 8, t1);
      i32x4 w0, w1;
      w0[0]=(int)t0[0]; w0[1]=(int)t0[1]; w0[2]=(int)t0[2]; w0[3]=(int)t0[3];
      w1[0]=(int)t1[0]; w1[1]=(int)t1[1]; w1[2]=(int)t1[2]; w1[3]=(int)t1[3];
      *reinterpret_cast<i32x4*>(kbuf + kw0) = w0;
      *reinterpret_cast<i32x4*>(kbuf + kw1) = w1;
    }
  };
  auto stageV = [&](uint8_t* vbuf, int kt) {
    if constexpr (sizeof(KVT) == 2) {
      const uint8_t* vb = (const uint8_t*)(Vsrc + kbase) + (size_t)kt * (KVROW * 2);
      #pragma unroll
      for (int ch = 0; ch < 2; ++ch) {
        __builtin_amdgcn_global_load_lds(
            (const __attribute__((address_space(1))) void*)(vb + vgo[ch]),
            (__attribute__((address_space(3))) void*)(vbuf + wv * 2048 + ch * 1024),
            16, 0, 0);
      }
    } else {
      // fp32: thread (va,vd) loads keys 2va,2va+1, dims vd*8..+7; each row's
      // 8 dims are one contiguous 16B chunk in the subtiled layout.
      const KVT* vs = vg + (size_t)(kt + 2 * va) * KVROW;
      uint32_t r0[4], r1[4];
      load8bf(vs, r0); load8bf(vs + KVROW, r1);
      const int D = vd >> 1, half = (vd & 1) * 16;
      const int k0 = 2 * va, k1 = k0 + 1;
      auto offB = [&](int k) {
        return (uint32_t)((D * 512 + ((k >> 2) & 1) * 256 + (k >> 3) * 64 + (k & 3) * 16) * 2 + half);
      };
      i32x4 w0, w1;
      w0[0]=(int)r0[0]; w0[1]=(int)r0[1]; w0[2]=(int)r0[2]; w0[3]=(int)r0[3];
      w1[0]=(int)r1[0]; w1[1]=(int)r1[1]; w1[2]=(int)r1[2]; w1[3]=(int)r1[3];
      *reinterpret_cast<i32x4*>(vbuf + offB(k0)) = w0;
      *reinterpret_cast<i32x4*>(vbuf + offB(k1)) = w1;
    }
  };

  const float SCALE2 = 0.08838834764831845f * 1.4426950408889634f;  // 1/sqrt(128)*log2e

  for (int rep = 0; rep < nrep; ++rep) {
    const int q0 = (rep ? qtB : qtA) * QB;

    // -------- Q fragments (bf16, SM_SCALE*log2e folded in) --------
    bf16x8 qf[2][4];
    #pragma unroll
    for (int tq = 0; tq < 2; ++tq) {
      const float* qp = Q + (size_t)(b * S_LEN + q0 + tq * 16 + c) * QROW + head * HD;
      #pragma unroll
      for (int f = 0; f < 4; ++f) {
        int d0 = f * 32 + g * 8;
        float4 a = *reinterpret_cast<const float4*>(qp + d0);
        float4 bb = *reinterpret_cast<const float4*>(qp + d0 + 4);
        i32x4 t;
        t[0] = (int)cvtpk(a.x * SCALE2, a.y * SCALE2);
        t[1] = (int)cvtpk(a.z * SCALE2, a.w * SCALE2);
        t[2] = (int)cvtpk(bb.x * SCALE2, bb.y * SCALE2);
        t[3] = (int)cvtpk(bb.z * SCALE2, bb.w * SCALE2);
        qf[tq][f] = __builtin_bit_cast(bf16x8, t);
      }
    }

    // online-softmax state (log2 domain); sink = initial column with weight 1,
    // split 0.25 per g-lane (lp is a per-lane partial of l, reduced at epilogue)
    float m_[2] = {sink_l2, sink_l2};
    float lp_[2] = {0.25f, 0.25f};
    f32x4 acc[2][8];
    #pragma unroll
    for (int tq = 0; tq < 2; ++tq)
      #pragma unroll
      for (int dt = 0; dt < 8; ++dt) acc[tq][dt] = (f32x4)0.0f;

    int kstart = q0 - (WIN - 1);
    if (kstart < 0) kstart = 0;
    kstart &= ~(KTILE - 1);

    uint8_t* kcur = smem;         uint8_t* kalt = smem + 8192;
    uint8_t* vcur = smem + 16384; uint8_t* valt = smem + 24576;
    uint32_t voff = 0;

    // prologue: stage first tile (all async on the bf16 path)
    stageK(kcur, kstart);
    stageV(vcur, kstart);
    __syncthreads();

    for (int kt = kstart; kt <= q0; kt += KTILE) {
      // unconditional clamped prefetch (last iter re-loads current tile; harmless)
      const int ktn = (kt + KTILE <= q0) ? (kt + KTILE) : kt;
      stageK(kalt, ktn);
      stageV(valt, ktn);

      // ---- QK^T (swapped: St[key-slot][q]) ----
      f32x4 st[2][2];
      #pragma unroll
      for (int a_ = 0; a_ < 2; ++a_)
        #pragma unroll
        for (int b_ = 0; b_ < 2; ++b_) st[a_][b_] = (f32x4)0.0f;

      __builtin_amdgcn_s_setprio(1);
      #pragma unroll
      for (int kt_ = 0; kt_ < 2; ++kt_) {
        bf16x8 kf[4];
        #pragma unroll
        for (int f = 0; f < 4; ++f) {
          int row = kt_ * 16 + c;
          uint32_t byte = (uint32_t)(row * 256 + ((f * 64 + g * 16) ^ ((row & 7) << 4)));
          kf[f] = *reinterpret_cast<const bf16x8*>(kcur + byte);
        }
        #pragma unroll
        for (int tq = 0; tq < 2; ++tq)
          #pragma unroll
          for (int f = 0; f < 4; ++f)
            st[kt_][tq] = __builtin_amdgcn_mfma_f32_16x16x32_bf16(kf[f], qf[tq][f], st[kt_][tq], 0, 0, 0);
      }
      __builtin_amdgcn_s_setprio(0);

      // ---- mask (edge tiles only; wave-uniform branch) ----
      // with KPERM, output element (kt_, r) of lane g is key g*8 + kt_*4 + r
      const bool need_mask = (kt + KTILE - 1 > q0) || (kt < q0 + QB - WIN);
      if (need_mask) {
        #pragma unroll
        for (int kt_ = 0; kt_ < 2; ++kt_)
          #pragma unroll
          for (int tq = 0; tq < 2; ++tq)
            #pragma unroll
            for (int r = 0; r < 4; ++r) {
              int k_ = kt + g * 8 + kt_ * 4 + r;
              int q_ = q0 + tq * 16 + c;
              bool ok = (k_ <= q_) && (k_ > q_ - WIN);
              if (!ok) st[kt_][tq][r] = -1e38f;
            }
      }

      // ---- online softmax (log2 domain, defer-rescale, lazy cross-lane),
      //      P assembled DIRECTLY into the PV A-fragment ----
      bf16x8 pa[2];
      #pragma unroll
      for (int tq = 0; tq < 2; ++tq) {
        float ownmax = fmaxf(fmaxf(fmaxf(st[0][tq][0], st[0][tq][1]), fmaxf(st[0][tq][2], st[0][tq][3])),
                             fmaxf(fmaxf(st[1][tq][0], st[1][tq][1]), fmaxf(st[1][tq][2], st[1][tq][3])));
        const float mold = m_[tq];
        if (!__all(ownmax <= mold + 11.54f)) {   // T13: P bounded by 2^11.54 = e^8
          float vmax = fmaxf(ownmax, __shfl_xor(ownmax, 16));
          vmax = fmaxf(vmax, __shfl_xor(vmax, 32));
          float mnew = fmaxf(mold, vmax);
          float scl  = exp2f(mold - mnew);
          m_[tq] = mnew;
          lp_[tq] *= scl;
          float sc[4];
          #pragma unroll
          for (int r = 0; r < 4; ++r) sc[r] = __shfl(scl, (lane & 48) | (g * 4 + r));
          #pragma unroll
          for (int dt = 0; dt < 8; ++dt)
            #pragma unroll
            for (int r = 0; r < 4; ++r) acc[tq][dt][r] *= sc[r];
        }
        const float mrun = m_[tq];
        float p[2][4];
        float s = 0.0f;
        #pragma unroll
        for (int kt_ = 0; kt_ < 2; ++kt_)
          #pragma unroll
          for (int r = 0; r < 4; ++r) {
            float e = exp2f(st[kt_][tq][r] - mrun);
            p[kt_][r] = e;
            s += e;
          }
        lp_[tq] += s;                       // per-lane partial; reduced at epilogue
        i32x4 pv;
        pv[0] = (int)cvtpk(p[0][0], p[0][1]);   // keys g*8+0, g*8+1
        pv[1] = (int)cvtpk(p[0][2], p[0][3]);   // keys g*8+2, g*8+3
        pv[2] = (int)cvtpk(p[1][0], p[1][1]);   // keys g*8+4, g*8+5
        pv[3] = (int)cvtpk(p[1][2], p[1][3]);   // keys g*8+6, g*8+7
        pa[tq] = __builtin_bit_cast(bf16x8, pv);
      }

      // ---- PV: B-frags via hardware transpose reads, 2-deep pipelined ----
      if constexpr (sizeof(KVT) == 2) {
        const uint32_t vaddr = vlane + voff;
        __builtin_amdgcn_s_setprio(1);
        __builtin_amdgcn_sched_barrier(0);     // keep compiler DS ops out of the counted window
        #define TR16(OFF) ({ u32x2 _r;                                                   \
            asm volatile("ds_read_b64_tr_b16 %0, %1 offset:%c2"                          \
                         : "=v"(_r) : "v"(vaddr), "i"(OFF)); _r; })
        u32x2 h0 = TR16(0), h1 = TR16(512);
        u32x2 n0, n1;
        #define PV_STEP(dt, LAST)                                                        \
          {                                                                              \
            if (!(LAST)) { n0 = TR16(((dt) + 1) * 1024); n1 = TR16(((dt) + 1) * 1024 + 512); } \
            asm volatile("s_waitcnt lgkmcnt(%c0)" :: "i"((LAST) ? 0 : 2) : "memory");    \
            __builtin_amdgcn_sched_barrier(0);                                           \
            i32x4 vv; vv[0]=(int)h0.x; vv[1]=(int)h0.y; vv[2]=(int)h1.x; vv[3]=(int)h1.y; \
            bf16x8 vf = __builtin_bit_cast(bf16x8, vv);                                  \
            acc[0][dt] = __builtin_amdgcn_mfma_f32_16x16x32_bf16(pa[0], vf, acc[0][dt], 0, 0, 0); \
            acc[1][dt] = __builtin_amdgcn_mfma_f32_16x16x32_bf16(pa[1], vf, acc[1][dt], 0, 0, 0); \
            h0 = n0; h1 = n1;                                                            \
          }
        PV_STEP(0,0) PV_STEP(1,0) PV_STEP(2,0) PV_STEP(3,0)
        PV_STEP(4,0) PV_STEP(5,0) PV_STEP(6,0) PV_STEP(7,1)
        #undef PV_STEP
        #undef TR16
        __builtin_amdgcn_s_setprio(0);
      } else {
        // fp32 fallback: read B-frags directly from the subtiled layout (scalar-ish, rare)
        __builtin_amdgcn_s_setprio(1);
        #pragma unroll
        for (int dt = 0; dt < 8; ++dt) {
          uint16_t e[8];
          #pragma unroll
          for (int jj = 0; jj < 8; ++jj) {
            uint32_t off = (uint32_t)((dt * 512 + (jj >> 2) * 256 + g * 64 + (jj & 3) * 16 + c) * 2);
            e[jj] = *reinterpret_cast<const uint16_t*>(vcur + off);
          }
          i32x4 vv;
          vv[0] = (int)((uint32_t)e[0] | ((uint32_t)e[1] << 16));
          vv[1] = (int)((uint32_t)e[2] | ((uint32_t)e[3] << 16));
          vv[2] = (int)((uint32_t)e[4] | ((uint32_t)e[5] << 16));
          vv[3] = (int)((uint32_t)e[6] | ((uint32_t)e[7] << 16));
          bf16x8 vf = __builtin_bit_cast(bf16x8, vv);
          #pragma unroll
          for (int tq = 0; tq < 2; ++tq)
            acc[tq][dt] = __builtin_amdgcn_mfma_f32_16x16x32_bf16(pa[tq], vf, acc[tq][dt], 0, 0, 0);
        }
        __builtin_amdgcn_s_setprio(0);
      }

      __syncthreads();
      uint8_t* t0 = kcur; kcur = kalt; kalt = t0;
      uint8_t* t1 = vcur; vcur = valt; valt = t1;
      voff ^= 8192;
    }

    // -------- epilogue: reduce l across g-lanes, O /= l, store --------
    #pragma unroll
    for (int tq = 0; tq < 2; ++tq) {
      float lt = lp_[tq];
      lt += __shfl_xor(lt, 16);
      lt += __shfl_xor(lt, 32);
      float linv = 1.0f / lt;
      float li[4];
      #pragma unroll
      for (int r = 0; r < 4; ++r) li[r] = __shfl(linv, (lane & 48) | (g * 4 + r));
      #pragma unroll
      for (int dt = 0; dt < 8; ++dt)
        #pragma unroll
        for (int r = 0; r < 4; ++r) {
          size_t o = (size_t)(b * S_LEN + q0 + tq * 16 + g * 4 + r) * QROW + head * HD + dt * 16 + c;
          out[o] = acc[tq][dt][r] * li[r];
        }
    }
  }
}

extern "C" void kernel_launch(void* const* d_in, const int* in_sizes, int n_in,
                              void* d_out, int out_size, void* d_ws, size_t ws_size,
                              hipStream_t stream) {
  const float* Q     = (const float*)d_in[0];
  const float* K     = (const float*)d_in[1];
  const float* V     = (const float*)d_in[2];
  const float* sinks = (const float*)d_in[3];
  float* out = (float*)d_out;

  const int nK = in_sizes[1];                       // B*S*NKV*HD
  const int B  = in_sizes[0] / (S_LEN * QROW);
  dim3 grid(384 * B);                               // 48 uniform blocks per (kv,b)

  const size_t need = (size_t)nK * 2u * 2u;         // Kbf + Vbf in bf16
  if (ws_size >= need) {
    uint16_t* Kb = (uint16_t*)d_ws;
    uint16_t* Vb = Kb + nK;
    cvt2_kernel<<<1024, 256, 0, stream>>>(K, V, Kb, Vb, nK / 4);
    attn_kernel<uint16_t><<<grid, 256, 0, stream>>>(Q, Kb, Vb, sinks, out);
  } else {
    attn_kernel<float><<<grid, 256, 0, stream>>>(Q, K, V, sinks, out);
  }
}